// Round 1
// baseline (889.338 us; speedup 1.0000x reference)
//
#include <hip/hip_runtime.h>

// ---------------------------------------------------------------------------
// Fused single-launch kernel.
//  - matched-dtype detection folded into every wave: each lane reads one uint4
//    of the first 1024 bytes of `matched` (L2-hot after the first block);
//    for int32 layout bytes at (i%4)!=0 are all zero; ~768 random payload
//    bytes inspected -> misdetection P ~ 2^-768. Removes detect_kernel launch
//    and the d_ws flag round-trip.
//  - role split by blockIdx: blocks [0, KFB) run the KF update (latency-bound,
//    ~200 VGPR, 2 waves/SIMD), blocks [KFB, ...) run the embedding EMA
//    (BW-bound). KF blocks dispatch first so their long-latency waves hide
//    under the embedding stream instead of running serially after it.
//  - emb role: 2 rows per wave (4 independent 16B loads in flight per lane)
//    to keep HBM saturated at the reduced fused occupancy.
// KF math is byte-identical to the previously verified kernel.
// ---------------------------------------------------------------------------

__device__ __forceinline__ bool get_matched(const void* mptr, int n, int flag)
{
    if (flag) return ((const unsigned char*)mptr)[n] != 0;
    return ((const int*)mptr)[n] != 0;
}

// fps arrives as a 1-elem array; tolerate int32 or float32 storage.
__device__ __forceinline__ float load_scalar_f(const int* p)
{
    int v = *p;
    if (v >= -1000000 && v <= 1000000) return (float)v;
    union { int i; float f; } u; u.i = v; return u.f;
}

__global__ __launch_bounds__(256, 2) void fused_kernel(
    const float* __restrict__ boxes,   // N,12
    const float* __restrict__ obs,     // N,7
    const float* __restrict__ pb7,     // N,7
    const float* __restrict__ pmean,   // N,10
    const float* __restrict__ pcov,    // N,10,10
    const float* __restrict__ pvel,    // N,7
    const float* __restrict__ pemb,    // N,256
    const float* __restrict__ emb,     // N,256
    const int*   __restrict__ accf,    // N
    const int*   __restrict__ fgap,    // N
    const void*  __restrict__ matched, // N (bool or int)
    const int*   __restrict__ fps_p,   // 1
    float* __restrict__ oboxes,        // N,12
    float* __restrict__ omean,         // N,10
    float* __restrict__ ocov,          // N,100
    float* __restrict__ ovel,          // N,7
    float* __restrict__ oemb,          // N,256
    float* __restrict__ oacc,          // N
    int N, int KFB)
{
    const int lane = threadIdx.x & 63;

    // ---- per-wave matched-dtype detect (all 64 lanes active here) ----
    const uint4 mv = ((const uint4*)matched)[lane];        // bytes 0..1023
    const unsigned bad = (mv.x | mv.y | mv.z | mv.w) & 0xFFFFFF00u;
    const int flag = (__ballot(bad != 0u) != 0ULL) ? 1 : 0; // 1 -> uint8 layout

    if ((int)blockIdx.x >= KFB) {
        // ================= embedding role: 2 rows per wave =================
        const int wid  = ((int)blockIdx.x - KFB) * 4 + ((int)threadIdx.x >> 6);
        const int row0 = wid * 2;
        if (row0 >= N) return;
        const bool have1 = (row0 + 1) < N;
        const size_t idx0 = (size_t)row0 * 64 + lane;

        const bool m0 = get_matched(matched, row0, flag);          // wave-uniform
        const bool m1 = have1 && get_matched(matched, row0 + 1, flag);

        const float4* e4 = (const float4*)emb;
        const float4* p4 = (const float4*)pemb;

        float4 e0 = e4[idx0];
        float4 e1;
        if (have1) e1 = e4[idx0 + 64];
        float4 p0, p1;
        if (m0) p0 = p4[idx0];
        if (m1) p1 = p4[idx0 + 64];

        float4 o0 = e0;
        if (m0) {
            o0.x = 0.2f * p0.x + 0.8f * e0.x;
            o0.y = 0.2f * p0.y + 0.8f * e0.y;
            o0.z = 0.2f * p0.z + 0.8f * e0.z;
            o0.w = 0.2f * p0.w + 0.8f * e0.w;
        }
        ((float4*)oemb)[idx0] = o0;
        if (have1) {
            float4 o1 = e1;
            if (m1) {
                o1.x = 0.2f * p1.x + 0.8f * e1.x;
                o1.y = 0.2f * p1.y + 0.8f * e1.y;
                o1.z = 0.2f * p1.z + 0.8f * e1.z;
                o1.w = 0.2f * p1.w + 0.8f * e1.w;
            }
            ((float4*)oemb)[idx0 + 64] = o1;
        }
        return;
    }

    // ==================== KF role (math unchanged) ====================
    const int n = (int)blockIdx.x * 256 + (int)threadIdx.x;
    if (n >= N) return;

    const bool m = get_matched(matched, n, flag);

    // obs needed in both paths (innov / mean_i)
    float ob[7];
#pragma unroll
    for (int j = 0; j < 7; j++) ob[j] = obs[(size_t)n * 7 + j];

    if (m) {
        const float fps = load_scalar_f(fps_p);

        // ---- load cov, keep only unique content: W (10x7) + V3 (3x3) ----
        float W[10][7], V3[3][3];
        {
            const float4* cp = (const float4*)(pcov + (size_t)n * 100);
#pragma unroll
            for (int i = 0; i < 25; i++) {
                float4 v = cp[i];
                float vv[4] = {v.x, v.y, v.z, v.w};
#pragma unroll
                for (int k = 0; k < 4; k++) {
                    const int e = 4 * i + k, l = e / 10, c = e % 10;
                    if (c < 7)            W[l][c]        = vv[k];
                    else if (l >= 7)      V3[l-7][c-7]   = vv[k];
                    // (l<7, c>=7): discarded, recovered via symmetry
                }
            }
        }
        float mu[10];
        {
            const float2* mp = (const float2*)(pmean + (size_t)n * 10);
#pragma unroll
            for (int i = 0; i < 5; i++) { float2 v = mp[i]; mu[2*i] = v.x; mu[2*i+1] = v.y; }
        }

        // ---- Cholesky: S = W[:7,:7] + I = L L^T (SPD by construction) ----
        float L[7][7];
#pragma unroll
        for (int k = 0; k < 7; k++) {
            float d = W[k][k] + 1.0f;
#pragma unroll
            for (int q = 0; q < k; q++) d -= L[k][q] * L[k][q];
            float dk = sqrtf(d);
            L[k][k] = dk;
            float inv = 1.0f / dk;
#pragma unroll
            for (int i = k + 1; i < 7; i++) {
                float s = W[i][k];
#pragma unroll
                for (int q = 0; q < k; q++) s -= L[i][q] * L[k][q];
                L[i][k] = s * inv;
            }
        }

        // ---- solve S X = PHt^T; rhs B[j][l] = cov[l][j] = W[l][j] ----
        float X[7][10];
#pragma unroll
        for (int j = 0; j < 7; j++) {                 // forward: L Y = B
            float rinv = 1.0f / L[j][j];
#pragma unroll
            for (int l = 0; l < 10; l++) {
                float s = W[l][j];
#pragma unroll
                for (int q = 0; q < j; q++) s -= L[j][q] * X[q][l];
                X[j][l] = s * rinv;
            }
        }
#pragma unroll
        for (int j = 6; j >= 0; j--) {                // back: L^T X = Y
            float rinv = 1.0f / L[j][j];
#pragma unroll
            for (int l = 0; l < 10; l++) {
                float s = X[j][l];
#pragma unroll
                for (int q = j + 1; q < 7; q++) s -= L[q][j] * X[q][l];
                X[j][l] = s * rinv;
            }
        }
        // L dead from here.

        // ---- mean update ----
        float innov[7];
#pragma unroll
        for (int j = 0; j < 7; j++) innov[j] = ob[j] - mu[j];
        float mu_u[10];
#pragma unroll
        for (int l = 0; l < 10; l++) {
            float s = mu[l];
#pragma unroll
            for (int j = 0; j < 7; j++) s += X[j][l] * innov[j];
            mu_u[l] = s;
        }
        // mu, ob, innov dead from here.

        // ---- cov_u = cov - PHt*X, streamed out float4 at a time ----
        {
            float4* op = (float4*)(ocov + (size_t)n * 100);
#pragma unroll
            for (int i = 0; i < 25; i++) {
                float r[4];
#pragma unroll
                for (int k = 0; k < 4; k++) {
                    const int e = 4 * i + k, l = e / 10, c = e % 10;
                    float base = (c < 7) ? W[l][c]
                               : ((l < 7) ? W[c][l] : V3[l-7][c-7]);
                    float s = 0.0f;
#pragma unroll
                    for (int j = 0; j < 7; j++) s += W[l][j] * X[j][c];
                    r[k] = base - s;
                }
                op[i] = make_float4(r[0], r[1], r[2], r[3]);
            }
        }
        // W, V3, X dead from here.

        // ---- boxes: [mu_u[0:6], bx6, bx7, mu_u[6], mu_u[7:10]*fps] ----
        // (pred_loc - mean_u[:3])[r] == mu_u[7+r] since F adds vel to pos.
        float bx6, bx7;
        {
            const float4* bp = (const float4*)(boxes + (size_t)n * 12);
            float4 b = bp[1];            // elements 4..7
            bx6 = b.z; bx7 = b.w;
        }
        {
            float4* op = (float4*)(oboxes + (size_t)n * 12);
            op[0] = make_float4(mu_u[0], mu_u[1], mu_u[2], mu_u[3]);
            op[1] = make_float4(mu_u[4], mu_u[5], bx6,     bx7);
            op[2] = make_float4(mu_u[6], mu_u[7] * fps, mu_u[8] * fps, mu_u[9] * fps);
        }
        {
            float2* op = (float2*)(omean + (size_t)n * 10);
#pragma unroll
            for (int i = 0; i < 5; i++) op[i] = make_float2(mu_u[2*i], mu_u[2*i+1]);
        }

        // ---- velocities / acc ----
        float gap  = (float)fgap[n];
        float acc  = (float)accf[n];
        float ginv = 1.0f / gap;
        float ainv = 1.0f / (acc + 1.0f);
#pragma unroll
        for (int j = 0; j < 7; j++) {
            float vobs = (mu_u[j] - pb7[(size_t)n*7 + j]) * ginv;
            ovel[(size_t)n*7 + j] = (pvel[(size_t)n*7 + j] * acc + vobs) * ainv;
        }
        oacc[n] = acc + 1.0f;
    } else {
        // unmatched: constant init / pass-through; no prev_* loads at all.
        {
            const float4* bp = (const float4*)(boxes + (size_t)n * 12);
            float4* op = (float4*)(oboxes + (size_t)n * 12);
            op[0] = bp[0]; op[1] = bp[1]; op[2] = bp[2];
        }
        {
            float2* op = (float2*)(omean + (size_t)n * 10);
            op[0] = make_float2(ob[0], ob[1]);
            op[1] = make_float2(ob[2], ob[3]);
            op[2] = make_float2(ob[4], ob[5]);
            op[3] = make_float2(ob[6], 0.0f);
            op[4] = make_float2(0.0f, 0.0f);
        }
        {
            float4* op = (float4*)(ocov + (size_t)n * 100);
#pragma unroll
            for (int i = 0; i < 25; i++) {
                float r[4];
#pragma unroll
                for (int k = 0; k < 4; k++) {
                    const int e = 4 * i + k, l = e / 10, c = e % 10;
                    r[k] = (l == c) ? ((l < 7) ? 10.0f : 10000.0f) : 0.0f;
                }
                op[i] = make_float4(r[0], r[1], r[2], r[3]);
            }
        }
#pragma unroll
        for (int j = 0; j < 7; j++) ovel[(size_t)n*7 + j] = 0.0f;
        oacc[n] = 0.0f;
    }
}

extern "C" void kernel_launch(void* const* d_in, const int* in_sizes, int n_in,
                              void* d_out, int out_size, void* d_ws, size_t ws_size,
                              hipStream_t stream)
{
    const float* boxes  = (const float*)d_in[0];
    const float* obs    = (const float*)d_in[1];
    const float* pb7    = (const float*)d_in[2];
    const float* pmean  = (const float*)d_in[3];
    const float* pcov   = (const float*)d_in[4];
    const float* pvel   = (const float*)d_in[5];
    const float* pemb   = (const float*)d_in[6];
    const float* emb    = (const float*)d_in[7];
    const int*   accf   = (const int*)d_in[8];
    const int*   fgap   = (const int*)d_in[9];
    const void*  matched= d_in[10];
    const int*   fps_p  = (const int*)d_in[11];
    const int N = in_sizes[8];   // acc_frames element count == N tracks

    float* out = (float*)d_out;
    float* oboxes = out;
    float* omean  = out + (size_t)N * 12;
    float* ocov   = out + (size_t)N * 22;
    float* ovel   = out + (size_t)N * 122;
    float* oemb   = out + (size_t)N * 129;
    float* oacc   = out + (size_t)N * 385;

    const int KFB = (N + 255) / 256;      // KF role blocks (dispatch first)
    const int EMB = (N + 7) / 8;          // emb role: 8 rows per 256-thr block
    fused_kernel<<<KFB + EMB, 256, 0, stream>>>(
        boxes, obs, pb7, pmean, pcov, pvel, pemb, emb, accf, fgap, matched,
        fps_p, oboxes, omean, ocov, ovel, oemb, oacc, N, KFB);
}